// Round 1
// baseline (1340.120 us; speedup 1.0000x reference)
//
#include <hip/hip_runtime.h>
#include <math.h>

// Problem dims
#define N_ 4
#define C_ 512
#define L_ 4096
#define D_ 256
#define K_ 8192
#define NL_ 16384           // N_*L_

// d_out layout (float32 flat): y | code_index(as float) | cb_loss | cm_loss
#define OUT_IDX_OFF (N_*C_*L_)          // 8388608
#define OUT_CB_OFF  (OUT_IDX_OFF + NL_) // 8404992
#define OUT_CM_OFF  (OUT_CB_OFF + N_)   // 8404996

// ws layout (float units). Total ~8.74M floats ~= 35 MB.
#define WS_ZT   0                                  // Zt[16384][256]
#define WS_P    (WS_ZT + (size_t)NL_*D_)           // P[8192][512]
#define WS_WIN  (WS_P + (size_t)K_*C_)             // W_in[256][512]
#define WS_WOUT (WS_WIN + (size_t)D_*C_)           // W_out[512][256]
#define WS_INVN (WS_WOUT + (size_t)C_*D_)          // inv codebook norms [8192]
#define WS_IDX  (WS_INVN + (size_t)K_)             // idx[16384] (int)
#define WS_LOSS (WS_IDX + (size_t)NL_)             // loss accum [4]

__device__ __forceinline__ void fma16(const float4 a, const float4 b, float (&acc)[4][4]) {
    acc[0][0] = fmaf(a.x, b.x, acc[0][0]); acc[0][1] = fmaf(a.x, b.y, acc[0][1]);
    acc[0][2] = fmaf(a.x, b.z, acc[0][2]); acc[0][3] = fmaf(a.x, b.w, acc[0][3]);
    acc[1][0] = fmaf(a.y, b.x, acc[1][0]); acc[1][1] = fmaf(a.y, b.y, acc[1][1]);
    acc[1][2] = fmaf(a.y, b.z, acc[1][2]); acc[1][3] = fmaf(a.y, b.w, acc[1][3]);
    acc[2][0] = fmaf(a.z, b.x, acc[2][0]); acc[2][1] = fmaf(a.z, b.y, acc[2][1]);
    acc[2][2] = fmaf(a.z, b.z, acc[2][2]); acc[2][3] = fmaf(a.z, b.w, acc[2][3]);
    acc[3][0] = fmaf(a.w, b.x, acc[3][0]); acc[3][1] = fmaf(a.w, b.y, acc[3][1]);
    acc[3][2] = fmaf(a.w, b.z, acc[3][2]); acc[3][3] = fmaf(a.w, b.w, acc[3][3]);
}

__device__ __forceinline__ float waveReduceSum64(float s) {
    #pragma unroll
    for (int off = 32; off; off >>= 1) s += __shfl_xor(s, off, 64);
    return s;
}

// ---------------------------------------------------------------------------
// prep: W_in = g*v/||v||, W_out likewise, inv codebook norms, zero loss accum.
// grid 8960 x 64 threads (one block per row).
// ---------------------------------------------------------------------------
__global__ __launch_bounds__(64) void prep_kernel(
    const float* __restrict__ in_v, const float* __restrict__ in_g,
    const float* __restrict__ out_v, const float* __restrict__ out_g,
    const float* __restrict__ cb,
    float* __restrict__ Win, float* __restrict__ Wout,
    float* __restrict__ invn, float* __restrict__ lossacc)
{
    const int b = blockIdx.x;
    const int t = threadIdx.x;
    if (b == 0 && t < N_) lossacc[t] = 0.0f;
    if (b < D_) {
        // row d of in_v (len 512)
        const float* v = in_v + (size_t)b * C_;
        float4 a0 = *(const float4*)(v + t * 4);
        float4 a1 = *(const float4*)(v + 256 + t * 4);
        float s = a0.x*a0.x + a0.y*a0.y + a0.z*a0.z + a0.w*a0.w
                + a1.x*a1.x + a1.y*a1.y + a1.z*a1.z + a1.w*a1.w;
        s = waveReduceSum64(s);
        float scale = in_g[b] / sqrtf(s);   // no eps per reference _wn
        float* w = Win + (size_t)b * C_;
        float4 o0, o1;
        o0.x=a0.x*scale; o0.y=a0.y*scale; o0.z=a0.z*scale; o0.w=a0.w*scale;
        o1.x=a1.x*scale; o1.y=a1.y*scale; o1.z=a1.z*scale; o1.w=a1.w*scale;
        *(float4*)(w + t*4) = o0;
        *(float4*)(w + 256 + t*4) = o1;
    } else if (b < D_ + C_) {
        // row c of out_v (len 256)
        const int r = b - D_;
        const float* v = out_v + (size_t)r * D_;
        float4 a0 = *(const float4*)(v + t * 4);
        float s = a0.x*a0.x + a0.y*a0.y + a0.z*a0.z + a0.w*a0.w;
        s = waveReduceSum64(s);
        float scale = out_g[r] / sqrtf(s);
        float4 o0;
        o0.x=a0.x*scale; o0.y=a0.y*scale; o0.z=a0.z*scale; o0.w=a0.w*scale;
        *(float4*)(Wout + (size_t)r * D_ + t*4) = o0;
    } else {
        // codebook row norms
        const int r = b - (D_ + C_);
        const float* v = cb + (size_t)r * D_;
        float4 a0 = *(const float4*)(v + t * 4);
        float s = a0.x*a0.x + a0.y*a0.y + a0.z*a0.z + a0.w*a0.w;
        s = waveReduceSum64(s);
        if (t == 0) invn[r] = 1.0f / fmaxf(sqrtf(s), 1e-8f);
    }
}

// ---------------------------------------------------------------------------
// z_e GEMM: Zt[n*L+l][d] = sum_c x[n][c][l] * Win[d][c] + in_b[d]
// tiles: 64 l x 64 d, K-chunks of 16 c, double-buffered LDS. 256 thr, 4x4 reg tile.
// grid (64, 4, 4) = (ltile, dtile, n)
// ---------------------------------------------------------------------------
__global__ __launch_bounds__(256) void ze_kernel(
    const float* __restrict__ x, const float* __restrict__ Win,
    const float* __restrict__ inb, float* __restrict__ Zt)
{
    __shared__ float Al[2][16][64];   // x tile [c][l]
    __shared__ float Bl[2][16][68];   // Win tile [c][d] (padded)
    const int tid = threadIdx.x;
    const int ty = tid >> 4, tx = tid & 15;
    const int l0 = blockIdx.x * 64;
    const int d0 = blockIdx.y * 64;
    const int n  = blockIdx.z;
    const float* xn = x + (size_t)n * C_ * L_;

    const int ac = tid >> 4, alq = tid & 15;   // A staging: 16 c x 16 float4 of l
    const int bd = tid >> 2, bq  = tid & 3;    // B staging: 64 d x 4 float4 of c

    float acc[4][4];
    #pragma unroll
    for (int i = 0; i < 4; ++i)
        #pragma unroll
        for (int j = 0; j < 4; ++j) acc[i][j] = 0.0f;

    auto stage = [&](int cc, int buf) {
        float4 av = *(const float4*)(xn + (size_t)(cc*16 + ac) * L_ + l0 + alq*4);
        *(float4*)&Al[buf][ac][alq*4] = av;
        float4 bv = *(const float4*)(Win + (size_t)(d0 + bd) * C_ + cc*16 + bq*4);
        Bl[buf][bq*4+0][bd] = bv.x; Bl[buf][bq*4+1][bd] = bv.y;
        Bl[buf][bq*4+2][bd] = bv.z; Bl[buf][bq*4+3][bd] = bv.w;
    };

    stage(0, 0);
    for (int cc = 0; cc < 32; ++cc) {
        __syncthreads();
        if (cc + 1 < 32) stage(cc + 1, (cc + 1) & 1);
        const int buf = cc & 1;
        #pragma unroll
        for (int k = 0; k < 16; ++k) {
            float4 a = *(const float4*)&Al[buf][k][ty*4];
            float4 b = *(const float4*)&Bl[buf][k][tx*4];
            fma16(a, b, acc);
        }
    }
    float4 bias = *(const float4*)(inb + d0 + tx*4);
    #pragma unroll
    for (int i = 0; i < 4; ++i) {
        float4 o;
        o.x = acc[i][0] + bias.x; o.y = acc[i][1] + bias.y;
        o.z = acc[i][2] + bias.z; o.w = acc[i][3] + bias.w;
        *(float4*)&Zt[(size_t)(n*L_ + l0 + ty*4 + i) * D_ + d0 + tx*4] = o;
    }
}

// ---------------------------------------------------------------------------
// P GEMM: P[k][c] = sum_d cb[k][d] * Wout[c][d]    (8192 x 512 x 256)
// grid (128, 8) = (ktile, ctile), tiles 64x64, chunks of 16 d.
// ---------------------------------------------------------------------------
__global__ __launch_bounds__(256) void pmat_kernel(
    const float* __restrict__ cb, const float* __restrict__ Wout,
    float* __restrict__ P)
{
    __shared__ float Al[2][16][68];   // cb tile [d][k]
    __shared__ float Bl[2][16][68];   // Wout tile [d][c]
    const int tid = threadIdx.x;
    const int ty = tid >> 4, tx = tid & 15;
    const int k0 = blockIdx.x * 64;
    const int c0 = blockIdx.y * 64;
    const int ar = tid >> 2, aq = tid & 3;

    float acc[4][4];
    #pragma unroll
    for (int i = 0; i < 4; ++i)
        #pragma unroll
        for (int j = 0; j < 4; ++j) acc[i][j] = 0.0f;

    auto stage = [&](int dc, int buf) {
        float4 av = *(const float4*)(cb + (size_t)(k0 + ar) * D_ + dc*16 + aq*4);
        Al[buf][aq*4+0][ar] = av.x; Al[buf][aq*4+1][ar] = av.y;
        Al[buf][aq*4+2][ar] = av.z; Al[buf][aq*4+3][ar] = av.w;
        float4 bv = *(const float4*)(Wout + (size_t)(c0 + ar) * D_ + dc*16 + aq*4);
        Bl[buf][aq*4+0][ar] = bv.x; Bl[buf][aq*4+1][ar] = bv.y;
        Bl[buf][aq*4+2][ar] = bv.z; Bl[buf][aq*4+3][ar] = bv.w;
    };

    stage(0, 0);
    for (int dc = 0; dc < 16; ++dc) {
        __syncthreads();
        if (dc + 1 < 16) stage(dc + 1, (dc + 1) & 1);
        const int buf = dc & 1;
        #pragma unroll
        for (int k = 0; k < 16; ++k) {
            float4 a = *(const float4*)&Al[buf][k][ty*4];
            float4 b = *(const float4*)&Bl[buf][k][tx*4];
            fma16(a, b, acc);
        }
    }
    #pragma unroll
    for (int i = 0; i < 4; ++i) {
        float4 o;
        o.x = acc[i][0]; o.y = acc[i][1]; o.z = acc[i][2]; o.w = acc[i][3];
        *(float4*)&P[(size_t)(k0 + ty*4 + i) * C_ + c0 + tx*4] = o;
    }
}

// ---------------------------------------------------------------------------
// sim + argmax: for each row m of Zt (16384), argmax_k dot(Zt[m], cb[k]) * invn[k].
// z_e normalization is a positive per-row scalar -> argmax-invariant -> skipped.
// Block: 32 rows, full D=256 resident in LDS; loop 64 K-tiles of 128 codes,
// double-buffered 16-d chunks. 256 thr = 8x32, 4x4 register tile.
// Running best in regs with first-index tie-break (matches jnp.argmax).
// LDS: 36864 + 16896 = 53.8 KB -> 2 blocks/CU resident (8 waves/CU).
// ---------------------------------------------------------------------------
__global__ __launch_bounds__(256, 2) void sim_kernel(
    const float* __restrict__ Zt, const float* __restrict__ cb,
    const float* __restrict__ invn, int* __restrict__ idxout,
    float* __restrict__ fidxout)
{
    __shared__ float Zl[256][36];        // [d][m], padded
    __shared__ float CBl[2][16][132];    // [dd][k], padded
    const int tid = threadIdx.x;
    const int ty = tid >> 5, tx = tid & 31;   // ty 0..7 (rows), tx 0..31 (cols)
    const int m0 = blockIdx.x * 32;

    // Stage Z tile (once): 32 rows x 256 d
    {
        const int m = tid >> 3, q = tid & 7;
        const float* zrow = Zt + (size_t)(m0 + m) * D_;
        #pragma unroll
        for (int it = 0; it < 8; ++it) {
            const int d4 = q + it * 8;
            float4 v = *(const float4*)(zrow + d4 * 4);
            Zl[d4*4+0][m] = v.x; Zl[d4*4+1][m] = v.y;
            Zl[d4*4+2][m] = v.z; Zl[d4*4+3][m] = v.w;
        }
    }

    const int sk = tid >> 1, sh = tid & 1;    // CB staging: 128 rows x 2 halves
    auto stageCB = [&](int kt, int dc, int buf) {
        const float* p = cb + (size_t)(kt*128 + sk) * D_ + dc*16 + sh*8;
        float4 v0 = *(const float4*)p;
        float4 v1 = *(const float4*)(p + 4);
        const int db = sh * 8;
        CBl[buf][db+0][sk] = v0.x; CBl[buf][db+1][sk] = v0.y;
        CBl[buf][db+2][sk] = v0.z; CBl[buf][db+3][sk] = v0.w;
        CBl[buf][db+4][sk] = v1.x; CBl[buf][db+5][sk] = v1.y;
        CBl[buf][db+6][sk] = v1.z; CBl[buf][db+7][sk] = v1.w;
    };

    float bestv[4]; int besti[4];
    #pragma unroll
    for (int i = 0; i < 4; ++i) { bestv[i] = -3.0e38f; besti[i] = 0; }

    stageCB(0, 0, 0);
    for (int kt = 0; kt < 64; ++kt) {
        float acc[4][4];
        #pragma unroll
        for (int i = 0; i < 4; ++i)
            #pragma unroll
            for (int j = 0; j < 4; ++j) acc[i][j] = 0.0f;

        #pragma unroll 2
        for (int dc = 0; dc < 16; ++dc) {
            __syncthreads();
            const int nc = kt * 16 + dc + 1;
            if (nc < 1024) stageCB(nc >> 4, nc & 15, (dc + 1) & 1);
            const int buf = dc & 1;
            #pragma unroll
            for (int dd = 0; dd < 16; ++dd) {
                float4 a = *(const float4*)&Zl[dc*16 + dd][ty*4];
                float4 b = *(const float4*)&CBl[buf][dd][tx*4];
                fma16(a, b, acc);
            }
        }
        // epilogue: scale by inv codebook norm, update running argmax
        const int kcol = kt * 128 + tx * 4;
        float4 iv = *(const float4*)(invn + kcol);
        const float ivv[4] = {iv.x, iv.y, iv.z, iv.w};
        #pragma unroll
        for (int j = 0; j < 4; ++j) {
            const int kk = kcol + j;
            #pragma unroll
            for (int i = 0; i < 4; ++i) {
                float v = acc[i][j] * ivv[j];
                if (v > bestv[i]) { bestv[i] = v; besti[i] = kk; }
            }
        }
    }

    // reduce across tx (32 lanes, same wave), tie -> smaller index
    #pragma unroll
    for (int i = 0; i < 4; ++i) {
        float v = bestv[i]; int ix = besti[i];
        #pragma unroll
        for (int off = 16; off; off >>= 1) {
            float ov = __shfl_xor(v, off, 32);
            int   oi = __shfl_xor(ix, off, 32);
            if (ov > v || (ov == v && oi < ix)) { v = ov; ix = oi; }
        }
        if (tx == 0) {
            const int r = m0 + ty*4 + i;
            idxout[r] = ix;
            fidxout[r] = (float)ix;
        }
    }
}

// ---------------------------------------------------------------------------
// losses: S[n] = sum_{l,d} (cb[idx[n,l]][d] - Zt[n*L+l][d])^2  (atomics into ws)
// grid 256 x 256; block handles 64 rows (all within one n).
// ---------------------------------------------------------------------------
__global__ __launch_bounds__(256) void loss_kernel(
    const float* __restrict__ Zt, const float* __restrict__ cb,
    const int* __restrict__ idx, float* __restrict__ lossacc)
{
    __shared__ float red[4];
    const int tid = threadIdx.x;
    const int r = blockIdx.x * 64 + (tid >> 2);
    const int q = tid & 3;
    const int n = r >> 12;
    const int code = idx[r];
    const float* zp = Zt + (size_t)r * D_ + q * 64;
    const float* cp = cb + (size_t)code * D_ + q * 64;
    float s = 0.0f;
    #pragma unroll
    for (int it = 0; it < 16; ++it) {
        float4 a = *(const float4*)(zp + it*4);
        float4 c = *(const float4*)(cp + it*4);
        float dx = c.x - a.x, dy = c.y - a.y, dz = c.z - a.z, dw = c.w - a.w;
        s += dx*dx + dy*dy + dz*dz + dw*dw;
    }
    s = waveReduceSum64(s);
    if ((tid & 63) == 0) red[tid >> 6] = s;
    __syncthreads();
    if (tid == 0) atomicAdd(&lossacc[n], red[0] + red[1] + red[2] + red[3]);
}

// ---------------------------------------------------------------------------
// y gather: y[n][c][l] = P[idx[n,l]][c] + out_b[c]
// grid (16, 4, 4) = (ltile 256, cchunk 128, n); 256 thr (one per l).
// ---------------------------------------------------------------------------
__global__ __launch_bounds__(256) void y_kernel(
    const float* __restrict__ P, const int* __restrict__ idx,
    const float* __restrict__ outb, float* __restrict__ y)
{
    __shared__ float bias[128];
    const int t = threadIdx.x;
    const int c0 = blockIdx.y * 128;
    const int n = blockIdx.z;
    const int l = blockIdx.x * 256 + t;
    if (t < 128) bias[t] = outb[c0 + t];
    __syncthreads();
    const int code = idx[n * L_ + l];
    const float* prow = P + (size_t)code * C_ + c0;
    float* yb = y + ((size_t)n * C_ + c0) * L_ + l;
    #pragma unroll 4
    for (int c = 0; c < 128; ++c) {
        yb[(size_t)c * L_] = prow[c] + bias[c];
    }
}

// ---------------------------------------------------------------------------
// finalize: cb_loss[n] = cm_loss[n] = S[n] / (D*L)
// ---------------------------------------------------------------------------
__global__ __launch_bounds__(64) void fin_kernel(
    const float* __restrict__ lossacc, float* __restrict__ out)
{
    const int t = threadIdx.x;
    if (t < 8) out[t] = lossacc[t & 3] * (1.0f / (float)(D_ * L_));
}

extern "C" void kernel_launch(void* const* d_in, const int* in_sizes, int n_in,
                              void* d_out, int out_size, void* d_ws, size_t ws_size,
                              hipStream_t stream) {
    (void)in_sizes; (void)n_in; (void)out_size; (void)ws_size;
    const float* x     = (const float*)d_in[0];
    const float* in_v  = (const float*)d_in[1];
    const float* in_g  = (const float*)d_in[2];
    const float* in_b  = (const float*)d_in[3];
    const float* out_v = (const float*)d_in[4];
    const float* out_g = (const float*)d_in[5];
    const float* out_b = (const float*)d_in[6];
    const float* cb    = (const float*)d_in[7];
    float* out = (float*)d_out;
    float* ws  = (float*)d_ws;

    float* Zt     = ws + WS_ZT;
    float* P      = ws + WS_P;
    float* Win    = ws + WS_WIN;
    float* Wout   = ws + WS_WOUT;
    float* invn   = ws + WS_INVN;
    int*   idx    = (int*)(ws + WS_IDX);
    float* lossac = ws + WS_LOSS;

    prep_kernel<<<dim3(D_ + C_ + K_), 64, 0, stream>>>(in_v, in_g, out_v, out_g, cb,
                                                       Win, Wout, invn, lossac);
    ze_kernel<<<dim3(64, 4, 4), 256, 0, stream>>>(x, Win, in_b, Zt);
    pmat_kernel<<<dim3(128, 8), 256, 0, stream>>>(cb, Wout, P);
    sim_kernel<<<dim3(512), 256, 0, stream>>>(Zt, cb, invn, idx, out + OUT_IDX_OFF);
    loss_kernel<<<dim3(256), 256, 0, stream>>>(Zt, cb, idx, lossac);
    y_kernel<<<dim3(16, 4, 4), 256, 0, stream>>>(P, idx, out_b, out);
    fin_kernel<<<dim3(1), 64, 0, stream>>>(lossac, out + OUT_CB_OFF);
}

// Round 2
// 1334.803 us; speedup vs baseline: 1.0040x; 1.0040x over previous
//
#include <hip/hip_runtime.h>
#include <math.h>

// Problem dims
#define N_ 4
#define C_ 512
#define L_ 4096
#define D_ 256
#define K_ 8192
#define NL_ 16384           // N_*L_

// d_out layout (float32 flat): y | code_index(as float) | cb_loss | cm_loss
#define OUT_IDX_OFF (N_*C_*L_)          // 8388608
#define OUT_CB_OFF  (OUT_IDX_OFF + NL_) // 8404992
#define OUT_CM_OFF  (OUT_CB_OFF + N_)   // 8404996

// ws layout (float units). Total ~10.77M floats ~= 43 MB.
#define WS_ZT   0                                  // Zt[16384][256]
#define WS_P    (WS_ZT + (size_t)NL_*D_)           // P[8192][512]
#define WS_CBT  (WS_P + (size_t)K_*C_)             // CBt[256][8192]
#define WS_WIN  (WS_CBT + (size_t)D_*K_)           // W_in[256][512]
#define WS_WOUT (WS_WIN + (size_t)D_*C_)           // W_out[512][256]
#define WS_INVN (WS_WOUT + (size_t)C_*D_)          // inv codebook norms [8192]
#define WS_IDX  (WS_INVN + (size_t)K_)             // idx[16384] (int)
#define WS_LOSS (WS_IDX + (size_t)NL_)             // loss accum [4]

__device__ __forceinline__ void fma16(const float4 a, const float4 b, float (&acc)[4][4]) {
    acc[0][0] = fmaf(a.x, b.x, acc[0][0]); acc[0][1] = fmaf(a.x, b.y, acc[0][1]);
    acc[0][2] = fmaf(a.x, b.z, acc[0][2]); acc[0][3] = fmaf(a.x, b.w, acc[0][3]);
    acc[1][0] = fmaf(a.y, b.x, acc[1][0]); acc[1][1] = fmaf(a.y, b.y, acc[1][1]);
    acc[1][2] = fmaf(a.y, b.z, acc[1][2]); acc[1][3] = fmaf(a.y, b.w, acc[1][3]);
    acc[2][0] = fmaf(a.z, b.x, acc[2][0]); acc[2][1] = fmaf(a.z, b.y, acc[2][1]);
    acc[2][2] = fmaf(a.z, b.z, acc[2][2]); acc[2][3] = fmaf(a.z, b.w, acc[2][3]);
    acc[3][0] = fmaf(a.w, b.x, acc[3][0]); acc[3][1] = fmaf(a.w, b.y, acc[3][1]);
    acc[3][2] = fmaf(a.w, b.z, acc[3][2]); acc[3][3] = fmaf(a.w, b.w, acc[3][3]);
}

__device__ __forceinline__ float waveReduceSum64(float s) {
    #pragma unroll
    for (int off = 32; off; off >>= 1) s += __shfl_xor(s, off, 64);
    return s;
}

// ---------------------------------------------------------------------------
// prep: W_in = g*v/||v||, W_out likewise, inv codebook norms, zero loss accum.
// ---------------------------------------------------------------------------
__global__ __launch_bounds__(64) void prep_kernel(
    const float* __restrict__ in_v, const float* __restrict__ in_g,
    const float* __restrict__ out_v, const float* __restrict__ out_g,
    const float* __restrict__ cb,
    float* __restrict__ Win, float* __restrict__ Wout,
    float* __restrict__ invn, float* __restrict__ lossacc)
{
    const int b = blockIdx.x;
    const int t = threadIdx.x;
    if (b == 0 && t < N_) lossacc[t] = 0.0f;
    if (b < D_) {
        const float* v = in_v + (size_t)b * C_;
        float4 a0 = *(const float4*)(v + t * 4);
        float4 a1 = *(const float4*)(v + 256 + t * 4);
        float s = a0.x*a0.x + a0.y*a0.y + a0.z*a0.z + a0.w*a0.w
                + a1.x*a1.x + a1.y*a1.y + a1.z*a1.z + a1.w*a1.w;
        s = waveReduceSum64(s);
        float scale = in_g[b] / sqrtf(s);
        float* w = Win + (size_t)b * C_;
        float4 o0, o1;
        o0.x=a0.x*scale; o0.y=a0.y*scale; o0.z=a0.z*scale; o0.w=a0.w*scale;
        o1.x=a1.x*scale; o1.y=a1.y*scale; o1.z=a1.z*scale; o1.w=a1.w*scale;
        *(float4*)(w + t*4) = o0;
        *(float4*)(w + 256 + t*4) = o1;
    } else if (b < D_ + C_) {
        const int r = b - D_;
        const float* v = out_v + (size_t)r * D_;
        float4 a0 = *(const float4*)(v + t * 4);
        float s = a0.x*a0.x + a0.y*a0.y + a0.z*a0.z + a0.w*a0.w;
        s = waveReduceSum64(s);
        float scale = out_g[r] / sqrtf(s);
        float4 o0;
        o0.x=a0.x*scale; o0.y=a0.y*scale; o0.z=a0.z*scale; o0.w=a0.w*scale;
        *(float4*)(Wout + (size_t)r * D_ + t*4) = o0;
    } else {
        const int r = b - (D_ + C_);
        const float* v = cb + (size_t)r * D_;
        float4 a0 = *(const float4*)(v + t * 4);
        float s = a0.x*a0.x + a0.y*a0.y + a0.z*a0.z + a0.w*a0.w;
        s = waveReduceSum64(s);
        if (t == 0) invn[r] = 1.0f / fmaxf(sqrtf(s), 1e-8f);
    }
}

// ---------------------------------------------------------------------------
// codebook transpose: CBt[d][k] = cb[k][d].  grid (256, 8), 32x32 tiles.
// ---------------------------------------------------------------------------
__global__ __launch_bounds__(256) void cbt_kernel(
    const float* __restrict__ cb, float* __restrict__ CBt)
{
    __shared__ float T[32][33];
    const int t = threadIdx.x;
    const int k0 = blockIdx.x * 32;
    const int d0 = blockIdx.y * 32;
    const int r = t >> 3, c4 = (t & 7) * 4;
    float4 v = *(const float4*)(cb + (size_t)(k0 + r) * D_ + d0 + c4);
    T[r][c4+0] = v.x; T[r][c4+1] = v.y; T[r][c4+2] = v.z; T[r][c4+3] = v.w;
    __syncthreads();
    float4 o;
    o.x = T[c4+0][r]; o.y = T[c4+1][r]; o.z = T[c4+2][r]; o.w = T[c4+3][r];
    *(float4*)(CBt + (size_t)(d0 + r) * K_ + k0 + c4) = o;
}

// ---------------------------------------------------------------------------
// z_e GEMM: Zt[n*L+l][d] = sum_c x[n][c][l] * Win[d][c] + in_b[d]
// ---------------------------------------------------------------------------
__global__ __launch_bounds__(256) void ze_kernel(
    const float* __restrict__ x, const float* __restrict__ Win,
    const float* __restrict__ inb, float* __restrict__ Zt)
{
    __shared__ float Al[2][16][64];   // x tile [c][l]
    __shared__ float Bl[2][16][68];   // Win tile [c][d] (padded)
    const int tid = threadIdx.x;
    const int ty = tid >> 4, tx = tid & 15;
    const int l0 = blockIdx.x * 64;
    const int d0 = blockIdx.y * 64;
    const int n  = blockIdx.z;
    const float* xn = x + (size_t)n * C_ * L_;

    const int ac = tid >> 4, alq = tid & 15;
    const int bd = tid >> 2, bq  = tid & 3;

    float acc[4][4];
    #pragma unroll
    for (int i = 0; i < 4; ++i)
        #pragma unroll
        for (int j = 0; j < 4; ++j) acc[i][j] = 0.0f;

    auto stage = [&](int cc, int buf) {
        float4 av = *(const float4*)(xn + (size_t)(cc*16 + ac) * L_ + l0 + alq*4);
        *(float4*)&Al[buf][ac][alq*4] = av;
        float4 bv = *(const float4*)(Win + (size_t)(d0 + bd) * C_ + cc*16 + bq*4);
        Bl[buf][bq*4+0][bd] = bv.x; Bl[buf][bq*4+1][bd] = bv.y;
        Bl[buf][bq*4+2][bd] = bv.z; Bl[buf][bq*4+3][bd] = bv.w;
    };

    stage(0, 0);
    for (int cc = 0; cc < 32; ++cc) {
        __syncthreads();
        if (cc + 1 < 32) stage(cc + 1, (cc + 1) & 1);
        const int buf = cc & 1;
        #pragma unroll
        for (int k = 0; k < 16; ++k) {
            float4 a = *(const float4*)&Al[buf][k][ty*4];
            float4 b = *(const float4*)&Bl[buf][k][tx*4];
            fma16(a, b, acc);
        }
    }
    float4 bias = *(const float4*)(inb + d0 + tx*4);
    #pragma unroll
    for (int i = 0; i < 4; ++i) {
        float4 o;
        o.x = acc[i][0] + bias.x; o.y = acc[i][1] + bias.y;
        o.z = acc[i][2] + bias.z; o.w = acc[i][3] + bias.w;
        *(float4*)&Zt[(size_t)(n*L_ + l0 + ty*4 + i) * D_ + d0 + tx*4] = o;
    }
}

// ---------------------------------------------------------------------------
// P GEMM: P[k][c] = sum_d cb[k][d] * Wout[c][d]    (8192 x 512 x 256)
// ---------------------------------------------------------------------------
__global__ __launch_bounds__(256) void pmat_kernel(
    const float* __restrict__ cb, const float* __restrict__ Wout,
    float* __restrict__ P)
{
    __shared__ float Al[2][16][68];
    __shared__ float Bl[2][16][68];
    const int tid = threadIdx.x;
    const int ty = tid >> 4, tx = tid & 15;
    const int k0 = blockIdx.x * 64;
    const int c0 = blockIdx.y * 64;
    const int ar = tid >> 2, aq = tid & 3;

    float acc[4][4];
    #pragma unroll
    for (int i = 0; i < 4; ++i)
        #pragma unroll
        for (int j = 0; j < 4; ++j) acc[i][j] = 0.0f;

    auto stage = [&](int dc, int buf) {
        float4 av = *(const float4*)(cb + (size_t)(k0 + ar) * D_ + dc*16 + aq*4);
        Al[buf][aq*4+0][ar] = av.x; Al[buf][aq*4+1][ar] = av.y;
        Al[buf][aq*4+2][ar] = av.z; Al[buf][aq*4+3][ar] = av.w;
        float4 bv = *(const float4*)(Wout + (size_t)(c0 + ar) * D_ + dc*16 + aq*4);
        Bl[buf][aq*4+0][ar] = bv.x; Bl[buf][aq*4+1][ar] = bv.y;
        Bl[buf][aq*4+2][ar] = bv.z; Bl[buf][aq*4+3][ar] = bv.w;
    };

    stage(0, 0);
    for (int dc = 0; dc < 16; ++dc) {
        __syncthreads();
        if (dc + 1 < 16) stage(dc + 1, (dc + 1) & 1);
        const int buf = dc & 1;
        #pragma unroll
        for (int k = 0; k < 16; ++k) {
            float4 a = *(const float4*)&Al[buf][k][ty*4];
            float4 b = *(const float4*)&Bl[buf][k][tx*4];
            fma16(a, b, acc);
        }
    }
    #pragma unroll
    for (int i = 0; i < 4; ++i) {
        float4 o;
        o.x = acc[i][0]; o.y = acc[i][1]; o.z = acc[i][2]; o.w = acc[i][3];
        *(float4*)&P[(size_t)(k0 + ty*4 + i) * C_ + c0 + tx*4] = o;
    }
}

// ---------------------------------------------------------------------------
// sim + argmax.  Per block: 64 m-rows, full D=256 of Z resident in LDS (64 KB,
// staged once, one barrier, then a sync-free k-loop).  Each wave owns 16 rows
// (A-reads are wave-uniform LDS broadcasts -> conflict-free); B streams from
// L2 via transposed codebook CBt[d][k] into registers, double-buffered one
// dd-stage (~256 VALU cyc) ahead of use.  Thread tile 16m x 8k = 128 acc.
// k-tiles of 512 (64 lanes x 8); argmax epilogue per tile; lane-reduce at end.
// ---------------------------------------------------------------------------
__global__ __launch_bounds__(256, 2) void sim_kernel(
    const float* __restrict__ Zt, const float* __restrict__ CBt,
    const float* __restrict__ invn, int* __restrict__ idxout,
    float* __restrict__ fidxout)
{
    __shared__ float Zl[256 * 64];     // [d][m], no pad (broadcast reads)
    const int tid = threadIdx.x;
    const int m0 = blockIdx.x * 64;

    // Stage Z tile: lane mm streams rows, coalesced ds_write_b32 across lanes.
    {
        const int mm = tid & 63;
        const int dg = tid >> 6;               // 4 d-groups of 64
        const float* zrow = Zt + (size_t)(m0 + mm) * D_ + dg * 64;
        #pragma unroll
        for (int it = 0; it < 16; ++it) {
            float4 v = *(const float4*)(zrow + it * 4);
            const int d = dg * 64 + it * 4;
            Zl[(d+0)*64 + mm] = v.x;
            Zl[(d+1)*64 + mm] = v.y;
            Zl[(d+2)*64 + mm] = v.z;
            Zl[(d+3)*64 + mm] = v.w;
        }
    }
    __syncthreads();

    const int j = tid & 63;                    // k lane
    const int w = tid >> 6;                    // wave id -> m sub-rows
    const float* aBase = Zl + w * 16;          // + dd*64

    float bestv[16]; int besti[16];
    #pragma unroll
    for (int r = 0; r < 16; ++r) { bestv[r] = -3.0e38f; besti[r] = 0; }

#define LOADA(dst, dd) { \
    const float* p_ = aBase + (dd) * 64; \
    *(float4*)&dst[0]  = *(const float4*)(p_); \
    *(float4*)&dst[4]  = *(const float4*)(p_ + 4); \
    *(float4*)&dst[8]  = *(const float4*)(p_ + 8); \
    *(float4*)&dst[12] = *(const float4*)(p_ + 12); }
#define LOADB(dst, dd) { \
    const float* q_ = bRow + (size_t)(dd) * K_; \
    *(float4*)&dst[0] = *(const float4*)(q_); \
    *(float4*)&dst[4] = *(const float4*)(q_ + 4); }
#define FMAB(A, B) { \
    _Pragma("unroll") \
    for (int r_ = 0; r_ < 16; ++r_) { \
        _Pragma("unroll") \
        for (int c_ = 0; c_ < 8; ++c_) \
            acc[r_][c_] = fmaf(A[r_], B[c_], acc[r_][c_]); } }

    for (int kt = 0; kt < 16; ++kt) {
        const int k0 = kt * 512;
        const float* bRow = CBt + k0 + j * 8;

        float acc[16][8];
        #pragma unroll
        for (int r = 0; r < 16; ++r)
            #pragma unroll
            for (int c = 0; c < 8; ++c) acc[r][c] = 0.0f;

        float aC[16], bC[8], aN[16], bN[8];
        LOADA(aC, 0); LOADB(bC, 0);
        for (int d2 = 0; d2 < 128; ++d2) {
            const int dd = d2 * 2;
            LOADA(aN, dd + 1); LOADB(bN, dd + 1);
            FMAB(aC, bC);
            if (d2 < 127) { LOADA(aC, dd + 2); LOADB(bC, dd + 2); }
            FMAB(aN, bN);
        }

        // epilogue: scale by inv codebook norm, update running argmax
        float iv[8];
        *(float4*)&iv[0] = *(const float4*)(invn + k0 + j*8);
        *(float4*)&iv[4] = *(const float4*)(invn + k0 + j*8 + 4);
        #pragma unroll
        for (int c = 0; c < 8; ++c) {
            const int kk = k0 + j*8 + c;
            const float s = iv[c];
            #pragma unroll
            for (int r = 0; r < 16; ++r) {
                float v = acc[r][c] * s;
                if (v > bestv[r]) { bestv[r] = v; besti[r] = kk; }
            }
        }
    }
#undef LOADA
#undef LOADB
#undef FMAB

    // reduce across the 64 lanes of the wave; tie -> smaller index
    #pragma unroll
    for (int r = 0; r < 16; ++r) {
        float v = bestv[r]; int ix = besti[r];
        #pragma unroll
        for (int off = 32; off; off >>= 1) {
            float ov = __shfl_xor(v, off, 64);
            int   oi = __shfl_xor(ix, off, 64);
            if (ov > v || (ov == v && oi < ix)) { v = ov; ix = oi; }
        }
        if (j == 0) {
            const int m = m0 + w*16 + r;
            idxout[m] = ix;
            fidxout[m] = (float)ix;
        }
    }
}

// ---------------------------------------------------------------------------
// losses: S[n] = sum_{l,d} (cb[idx[n,l]][d] - Zt[n*L+l][d])^2
// ---------------------------------------------------------------------------
__global__ __launch_bounds__(256) void loss_kernel(
    const float* __restrict__ Zt, const float* __restrict__ cb,
    const int* __restrict__ idx, float* __restrict__ lossacc)
{
    __shared__ float red[4];
    const int tid = threadIdx.x;
    const int r = blockIdx.x * 64 + (tid >> 2);
    const int q = tid & 3;
    const int n = r >> 12;
    const int code = idx[r];
    const float* zp = Zt + (size_t)r * D_ + q * 64;
    const float* cp = cb + (size_t)code * D_ + q * 64;
    float s = 0.0f;
    #pragma unroll
    for (int it = 0; it < 16; ++it) {
        float4 a = *(const float4*)(zp + it*4);
        float4 c = *(const float4*)(cp + it*4);
        float dx = c.x - a.x, dy = c.y - a.y, dz = c.z - a.z, dw = c.w - a.w;
        s += dx*dx + dy*dy + dz*dz + dw*dw;
    }
    s = waveReduceSum64(s);
    if ((tid & 63) == 0) red[tid >> 6] = s;
    __syncthreads();
    if (tid == 0) atomicAdd(&lossacc[n], red[0] + red[1] + red[2] + red[3]);
}

// ---------------------------------------------------------------------------
// y gather: y[n][c][l] = P[idx[n,l]][c] + out_b[c]
// ---------------------------------------------------------------------------
__global__ __launch_bounds__(256) void y_kernel(
    const float* __restrict__ P, const int* __restrict__ idx,
    const float* __restrict__ outb, float* __restrict__ y)
{
    __shared__ float bias[128];
    const int t = threadIdx.x;
    const int c0 = blockIdx.y * 128;
    const int n = blockIdx.z;
    const int l = blockIdx.x * 256 + t;
    if (t < 128) bias[t] = outb[c0 + t];
    __syncthreads();
    const int code = idx[n * L_ + l];
    const float* prow = P + (size_t)code * C_ + c0;
    float* yb = y + ((size_t)n * C_ + c0) * L_ + l;
    #pragma unroll 4
    for (int c = 0; c < 128; ++c) {
        yb[(size_t)c * L_] = prow[c] + bias[c];
    }
}

__global__ __launch_bounds__(64) void fin_kernel(
    const float* __restrict__ lossacc, float* __restrict__ out)
{
    const int t = threadIdx.x;
    if (t < 8) out[t] = lossacc[t & 3] * (1.0f / (float)(D_ * L_));
}

extern "C" void kernel_launch(void* const* d_in, const int* in_sizes, int n_in,
                              void* d_out, int out_size, void* d_ws, size_t ws_size,
                              hipStream_t stream) {
    (void)in_sizes; (void)n_in; (void)out_size; (void)ws_size;
    const float* x     = (const float*)d_in[0];
    const float* in_v  = (const float*)d_in[1];
    const float* in_g  = (const float*)d_in[2];
    const float* in_b  = (const float*)d_in[3];
    const float* out_v = (const float*)d_in[4];
    const float* out_g = (const float*)d_in[5];
    const float* out_b = (const float*)d_in[6];
    const float* cb    = (const float*)d_in[7];
    float* out = (float*)d_out;
    float* ws  = (float*)d_ws;

    float* Zt     = ws + WS_ZT;
    float* P      = ws + WS_P;
    float* CBt    = ws + WS_CBT;
    float* Win    = ws + WS_WIN;
    float* Wout   = ws + WS_WOUT;
    float* invn   = ws + WS_INVN;
    int*   idx    = (int*)(ws + WS_IDX);
    float* lossac = ws + WS_LOSS;

    prep_kernel<<<dim3(D_ + C_ + K_), 64, 0, stream>>>(in_v, in_g, out_v, out_g, cb,
                                                       Win, Wout, invn, lossac);
    cbt_kernel<<<dim3(256, 8), 256, 0, stream>>>(cb, CBt);
    ze_kernel<<<dim3(64, 4, 4), 256, 0, stream>>>(x, Win, in_b, Zt);
    pmat_kernel<<<dim3(128, 8), 256, 0, stream>>>(cb, Wout, P);
    sim_kernel<<<dim3(256), 256, 0, stream>>>(Zt, CBt, invn, idx, out + OUT_IDX_OFF);
    loss_kernel<<<dim3(256), 256, 0, stream>>>(Zt, cb, idx, lossac);
    y_kernel<<<dim3(16, 4, 4), 256, 0, stream>>>(P, idx, out_b, out);
    fin_kernel<<<dim3(1), 64, 0, stream>>>(lossac, out + OUT_CB_OFF);
}